// Round 7
// baseline (178.200 us; speedup 1.0000x reference)
//
#include <hip/hip_runtime.h>

#define T 8192
#define BATCH 512
#define NTH 1024
#define EPT 8
#define NW 16

typedef float nfloat4 __attribute__((ext_vector_type(4)));

template <int N>
__device__ __forceinline__ void block_reduce(float (&v)[N], float* s_red, float* s_bc) {
    int lane = threadIdx.x & 63, wid = threadIdx.x >> 6;
#pragma unroll
    for (int j = 0; j < N; j++) {
        float x = v[j];
#pragma unroll
        for (int off = 32; off; off >>= 1) x += __shfl_xor(x, off);
        if (lane == 0) s_red[wid * N + j] = x;
    }
    __syncthreads();
    if (threadIdx.x < N) {
        float s = 0.f;
#pragma unroll
        for (int w = 0; w < NW; w++) s += s_red[w * N + threadIdx.x];
        s_bc[threadIdx.x] = s;
    }
    __syncthreads();
}

__global__ __launch_bounds__(NTH) void teacher_kernel(
    const float* __restrict__ dur, const float* __restrict__ stats,
    const float* __restrict__ trace, const float* __restrict__ mask,
    const float* __restrict__ cue, float* __restrict__ out)
{
    const int row = blockIdx.x;
    const int tid = threadIdx.x;
    const int lane = tid & 63, wid = tid >> 6;
    const int base = tid * EPT;

    __shared__ unsigned s_hist[2 * NW * 256];   // 32 KB ping-pong
    __shared__ float s_red[NW * 13];
    __shared__ float s_bc[16];
    __shared__ float s_c0[NTH];                 // each thread's cue[base]
    __shared__ float s_vf[NTH];                 // raw score v[0] per thread
    __shared__ float s_vl[NTH];                 // raw score v[7] per thread
    __shared__ float s_ws[NW];
    __shared__ unsigned s_sel[4];
    __shared__ unsigned s_wu[NW];

    const size_t BT = (size_t)BATCH * T;
    const size_t rbase = (size_t)row * T;

    const float4* m4 = (const float4*)(mask + rbase);
    const float4* d4 = (const float4*)(dur + rbase);
    const float4* c4 = (const float4*)(cue + rbase);
    const float4* t4 = (const float4*)(trace + rbase * 4);

    float* o_sb  = out + 2 * BT;
    float* o_pb  = out + 2 * BT + BATCH;
    float* o_cf  = out + 3 * BT + 2 * BATCH;
    nfloat4* spe4 = (nfloat4*)(out + rbase);
    nfloat4* pae4 = (nfloat4*)(out + BT + rbase);
    nfloat4* al4  = (nfloat4*)(out + 2 * BT + 2 * BATCH + rbase);
    nfloat4* tc4  = ((nfloat4*)(out + 3 * BT + 3 * BATCH)) + rbase;
    nfloat4* pc4  = (nfloat4*)(out + 7 * BT + 3 * BATCH + rbase);
    nfloat4* bk4  = (nfloat4*)(out + 8 * BT + 3 * BATCH + rbase);

    float durr[EPT];

    // ---- Phase 1: full input read (all float4), write trace_ctx, 12 masked sums + stats max
    float statmax = (tid < BATCH) ? fminf(fmaxf(stats[tid * 5 + 4], 0.f), 1.f) : 0.f;
    float acc[12];
#pragma unroll
    for (int j = 0; j < 12; j++) acc[j] = 0.f;
#pragma unroll
    for (int h = 0; h < 2; h++) {
        float4 mm = m4[tid * 2 + h];
        float4 dd = d4[tid * 2 + h];
        float4 cc = c4[tid * 2 + h];
        float4 tt[4];
        tt[0] = t4[base + 4 * h + 0];
        tt[1] = t4[base + 4 * h + 1];
        tt[2] = t4[base + 4 * h + 2];
        tt[3] = t4[base + 4 * h + 3];
        if (h == 0) s_c0[tid] = cc.x;
        const float* mp = &mm.x; const float* dp = &dd.x; const float* cp = &cc.x;
#pragma unroll
        for (int j = 0; j < 4; j++) {
            float m = mp[j], d = dp[j], c = cp[j];
            float4 tr = tt[j];
            durr[4 * h + j] = d;
            nfloat4 tcv = {tr.x * m, tr.y * m, tr.z * m, tr.w * m};
            __builtin_nontemporal_store(tcv, &tc4[base + 4 * h + j]);
            acc[0] += m;            acc[1] += d * m;
            acc[2] += tr.x * m;     acc[3] += tr.x * tr.x * m;
            acc[4] += tr.y * m;     acc[5] += tr.y * tr.y * m;
            acc[6] += tr.z * m;     acc[7] += tr.z * tr.z * m;
            acc[8] += tr.w * m;     acc[9] += tr.w * tr.w * m;
            acc[10] += c * m;       acc[11] += c * tr.z * m;
        }
    }
    {
#pragma unroll
        for (int j = 0; j < 12; j++) {
            float x = acc[j];
#pragma unroll
            for (int off = 32; off; off >>= 1) x += __shfl_xor(x, off);
            if (lane == 0) s_red[wid * 13 + j] = x;
        }
        float mx = statmax;
#pragma unroll
        for (int off = 32; off; off >>= 1) mx = fmaxf(mx, __shfl_xor(mx, off));
        if (lane == 0) s_red[wid * 13 + 12] = mx;
        __syncthreads();
        if (tid < 13) {
            float s = s_red[tid];
#pragma unroll
            for (int w = 1; w < NW; w++) {
                float x = s_red[w * 13 + tid];
                s = (tid == 12) ? fmaxf(s, x) : (s + x);
            }
            s_bc[tid] = s;
        }
        __syncthreads();
    }
    const float visible = fmaxf(s_bc[0], 1.f);
    const float sum_d = s_bc[1];
    const float inv_vis = 1.f / visible;
    const float mean0 = s_bc[2] * inv_vis, ex20 = s_bc[3] * inv_vis;
    const float mean1 = s_bc[4] * inv_vis, ex21 = s_bc[5] * inv_vis;
    const float Sz    = s_bc[6];
    const float mean2 = Sz * inv_vis,      ex22 = s_bc[7] * inv_vis;
    const float mean3 = s_bc[8] * inv_vis, ex23 = s_bc[9] * inv_vis;
    const float n1    = s_bc[10];
    const float Scz   = s_bc[11];
    const float gmax  = s_bc[12];
    const float meanc = n1 * inv_vis;

    const float var1_raw = ex21 - mean1 * mean1;
    const float var2_raw = ex22 - mean2 * mean2;
    const float istd0 = 1.f / sqrtf(fmaxf(ex20 - mean0 * mean0, 1e-6f));
    const float istd1 = 1.f / sqrtf(fmaxf(var1_raw, 1e-6f));
    const float istd2 = 1.f / sqrtf(fmaxf(var2_raw, 1e-6f));
    const float istd3 = 1.f / sqrtf(fmaxf(ex23 - mean3 * mean3, 1e-6f));
    const float istdc = 1.f / sqrtf(fmaxf(meanc - meanc * meanc, 1e-6f));

    const int L = (int)(visible + 0.5f);

    const float st0 = stats[row * 5 + 0], st1 = stats[row * 5 + 1];
    const float st2 = stats[row * 5 + 2], st4 = stats[row * 5 + 4];

    const float src_total = fmaxf(sum_d, 1.f);
    const float src_mean = src_total * inv_vis;
    const float ref_ms = fmaxf(st2, 1.f);
    const float rate_scale = fminf(fmaxf(ref_ms / fmaxf(src_mean, 1.f), 0.55f), 1.95f);
    const float speech_budget = src_total * rate_scale;
    const float pause_ratio = fminf(fmaxf(st0, 0.f), 0.49f);
    const float boundary_ratio = fminf(fmaxf(st4, 0.f), 1.f);
    const float mean_pause = fmaxf(st1, 0.f);
    const float pfr = speech_budget * pause_ratio / fmaxf(1.f - pause_ratio, 0.2f);
    const float pfe = visible * boundary_ratio * mean_pause;
    float pause_budget = fmaxf(0.35f * pfr + 0.65f * pfe, 0.f);
    pause_budget = fminf(pause_budget, speech_budget * 0.8f);

    float conf = 0.2f + 0.3f * fminf(fmaxf(st0, 0.f), 1.f)
               + 0.25f * fminf(fmaxf(st4, 0.f), 1.f)
               + 0.2f * mean2
               + 0.1f * expf(-fmaxf(var1_raw, 0.f)) + 0.05f;
    conf = fminf(fmaxf(conf, 0.05f), 1.f);

    const float ratio = fminf(fmaxf(fmaxf(0.3f, gmax), 0.f), 1.f);
    int kint = (int)rintf(visible * ratio);
    kint = max(1, min(kint, L));

    // ---- Closed-form cosine gate (cue is 0/1: sp takes two values hi/lo)
    const float hi = fminf(fmaxf((1.f - meanc) * istdc, -1.5f), 1.5f);
    const float lo = fminf(fmaxf((0.f - meanc) * istdc, -1.5f), 1.5f);
    float pcoef;
    {
        float n0 = visible - n1;
        float sum_sp2 = hi * hi * n1 + lo * lo * n0;
        float sum_rb2 = istd2 * istd2 * visible * fmaxf(var2_raw, 0.f);
        float c1 = Scz - mean2 * n1;
        float c0 = (Sz - mean2 * visible) - c1;
        float dotv = istd2 * (hi * c1 + lo * c0);
        float xn = sqrtf(fmaxf(sum_sp2, 1e-6f));
        float yn = sqrtf(fmaxf(sum_rb2, 1e-6f));
        float agree = fminf(fmaxf(dotv / fmaxf(xn * yn, 1e-6f), -1.f), 1.f);
        float gate = 1.f / (1.f + expf(-(agree - 0.15f) * 4.f));
        pcoef = 0.35f * (0.05f + 0.5f * gate);
    }

    // ---- Phase 3: speech + pause scores (cue/trace reloads are L3-hot, float4)
    float v[EPT], ps[EPT];
    {
        float4 ca = c4[tid * 2], cb = c4[tid * 2 + 1];
        const float* cap = &ca.x; const float* cbp = &cb.x;
#pragma unroll
        for (int h = 0; h < 2; h++) {
            float4 tt[4];
            tt[0] = t4[base + 4 * h + 0];
            tt[1] = t4[base + 4 * h + 1];
            tt[2] = t4[base + 4 * h + 2];
            tt[3] = t4[base + 4 * h + 3];
#pragma unroll
            for (int j = 0; j < 4; j++) {
                int i = 4 * h + j;
                int t = base + i;
                float c = h ? cbp[j] : cap[j];
                float pf;
                if (i < 3)       pf = cap[i + 1];
                else if (i == 3) pf = cbp[0];
                else if (i < 7)  pf = cbp[i - 3];
                else             pf = (tid == NTH - 1) ? 1.f : s_c0[tid + 1];
                float4 tr = tt[j];
                float vv = 0.f, pp = 0.f;
                if (t < L) {
                    float z1 = (tr.y - mean1) * istd1;
                    float z3 = (tr.w - mean3) * istd3;
                    vv = expf(log1pf(fmaxf(durr[i], 0.f)) + 0.45f * z1 + 0.3f * z3 + 0.2f * pf);
                    float z0 = (tr.x - mean0) * istd0;
                    float rbv = (tr.z - mean2) * istd2;
                    float spv = lo + c * (hi - lo);
                    pp = expf(1.1f * z0 + 1.5f * rbv + pcoef * spv);
                }
                v[i] = vv; ps[i] = pp;
            }
        }
    }
    s_vf[tid] = v[0];
    s_vl[tid] = v[7];
    // clear radix hist buffer 0 under the same barrier
    for (int j = tid; j < NW * 256; j += NTH) s_hist[j] = 0u;
    __syncthreads();

    // ---- Phase 3b: smooth3 in-register (edges via LDS); sum
    float acc1[1] = {0.f};
    {
        float prev = (tid > 0) ? s_vl[tid - 1] : 0.f;
        float nxt_edge = (tid < NTH - 1) ? s_vf[tid + 1] : 0.f;
#pragma unroll
        for (int i = 0; i < EPT; i++) {
            float cur = v[i];
            float nxt = (i < 7) ? v[i + 1] : nxt_edge;
            float smv = (base + i < L) ? (prev + cur + nxt) * (1.f / 3.f) : 0.f;
            v[i] = smv; acc1[0] += smv; prev = cur;
        }
    }
    block_reduce<1>(acc1, s_red, s_bc);
    const float spe_scale = speech_budget / fmaxf(s_bc[0], 1e-6f);

    // ---- Phase 4: exact radix select, ping-pong histograms (2 barriers/round)
    unsigned pref = 0u, cmaskk = 0u;
    unsigned kk = (unsigned)kint;
    unsigned cnt_eq = 0u;
    int cur = 0;
#pragma unroll 1
    for (int r = 0; r < 4; r++) {
        const int shift = 24 - 8 * r;
#pragma unroll
        for (int i = 0; i < EPT; i++) {
            unsigned b = __float_as_uint(ps[i]);
            if ((b & cmaskk) == pref)
                atomicAdd(&s_hist[cur * (NW * 256) + wid * 256 + ((b >> shift) & 0xFFu)], 1u);
        }
        __syncthreads();
        if (wid == 0) {
            unsigned bb = lane * 4;
            unsigned h0 = 0, h1 = 0, h2 = 0, h3 = 0;
#pragma unroll
            for (int w = 0; w < NW; w++) {
                const unsigned* hb = &s_hist[cur * (NW * 256) + w * 256 + bb];
                h0 += hb[0]; h1 += hb[1]; h2 += hb[2]; h3 += hb[3];
            }
            unsigned s = h0 + h1 + h2 + h3;
            unsigned vs = s;
#pragma unroll
            for (int off = 1; off < 64; off <<= 1) {
                unsigned u = __shfl_down(vs, off);
                if (lane + off < 64) vs += u;
            }
            unsigned vnext = __shfl_down(vs, 1);
            if (lane == 63) vnext = 0u;
            unsigned higher = vs - s;
            unsigned S3 = higher + h3;
            unsigned S2 = S3 + h2;
            unsigned S1 = S2 + h1;
            unsigned S0 = S1 + h0;
            if (S3 >= kk && vnext < kk)    { s_sel[0] = bb + 3; s_sel[1] = vnext; s_sel[2] = S3; }
            else if (S2 >= kk && S3 < kk)  { s_sel[0] = bb + 2; s_sel[1] = S3;    s_sel[2] = S2; }
            else if (S1 >= kk && S2 < kk)  { s_sel[0] = bb + 1; s_sel[1] = S2;    s_sel[2] = S1; }
            else if (S0 >= kk && S1 < kk)  { s_sel[0] = bb + 0; s_sel[1] = S1;    s_sel[2] = S0; }
        } else if (r < 3) {
            for (int j = tid - 64; j < NW * 256; j += NTH - 64)
                s_hist[(cur ^ 1) * (NW * 256) + j] = 0u;
        }
        __syncthreads();
        pref |= s_sel[0] << shift;
        cmaskk |= 0xFFu << shift;
        kk -= s_sel[1];
        if (r == 3) cnt_eq = s_sel[2] - s_sel[1];
        cur ^= 1;
    }
    const unsigned thr_bits = pref;
    const unsigned keep_eq = kk;

    // ---- Phase 5: keep top-k; stable ascending-index tie-break only if ties span the cut
    float accp[1] = {0.f};
    if (cnt_eq == keep_eq) {
#pragma unroll
        for (int c = 0; c < EPT; c++) {
            unsigned b = __float_as_uint(ps[c]);
            float pv = (b >= thr_bits) ? ps[c] : 0.f;
            ps[c] = pv; accp[0] += pv;
        }
    } else {
        unsigned teq = 0;
#pragma unroll
        for (int i = 0; i < EPT; i++) teq += (__float_as_uint(ps[i]) == thr_bits) ? 1u : 0u;
        unsigned winc = teq;
#pragma unroll
        for (int off = 1; off < 64; off <<= 1) {
            unsigned u = __shfl_up(winc, off);
            if (lane >= off) winc += u;
        }
        if (lane == 63) s_wu[wid] = winc;
        __syncthreads();
        unsigned rank = winc - teq;
#pragma unroll
        for (int w = 0; w < NW; w++) if (w < wid) rank += s_wu[w];
#pragma unroll
        for (int c = 0; c < EPT; c++) {
            unsigned b = __float_as_uint(ps[c]);
            bool eq = (b == thr_bits);
            bool keep = (b > thr_bits) || (eq && rank < keep_eq);
            if (eq) rank++;
            float pv = keep ? ps[c] : 0.f;
            ps[c] = pv; accp[0] += pv;
        }
    }
    block_reduce<1>(accp, s_red, s_bc);
    const float pa_scale = pause_budget / fmaxf(s_bc[0], 1e-6f);

    // ---- Phase 6: packed float4 writes + thread-local prefix + 1-barrier block scan
    const float inv_alloc = 1.f / fmaxf(speech_budget + pause_budget, 1e-6f);
    float run = 0.f;
#pragma unroll
    for (int g = 0; g < 2; g++) {
        nfloat4 s4, p4, a4;
#pragma unroll
        for (int j = 0; j < 4; j++) {
            int i = g * 4 + j;
            bool in = base + i < L;
            float spe = v[i] * spe_scale;
            float pae = ps[i] * pa_scale;
            s4[j] = spe;
            p4[j] = pae;
            a4[j] = (spe + pae) * inv_alloc;
            float x = in ? (spe + pae - durr[i]) : 0.f;
            run += x;
            durr[i] = run;               // reuse durr as local inclusive scan
        }
        __builtin_nontemporal_store(s4, &spe4[tid * 2 + g]);
        __builtin_nontemporal_store(p4, &pae4[tid * 2 + g]);
        __builtin_nontemporal_store(a4, &al4[tid * 2 + g]);
    }
    {
        float total = run;
        float winc = total;
#pragma unroll
        for (int off = 1; off < 64; off <<= 1) {
            float u = __shfl_up(winc, off);
            if (lane >= off) winc += u;
        }
        if (lane == 63) s_ws[wid] = winc;
        __syncthreads();
        float off0 = winc - total;
#pragma unroll
        for (int w = 0; w < NW; w++) if (w < wid) off0 += s_ws[w];
#pragma unroll
        for (int g = 0; g < 2; g++) {
            nfloat4 pcv, bkv;
#pragma unroll
            for (int j = 0; j < 4; j++) {
                int i = g * 4 + j;
                bool in = base + i < L;
                float incl = off0 + durr[i];
                pcv[j] = in ? incl : 0.f;
                bkv[j] = in ? fmaxf(incl, 0.f) : 0.f;
            }
            __builtin_nontemporal_store(pcv, &pc4[tid * 2 + g]);
            __builtin_nontemporal_store(bkv, &bk4[tid * 2 + g]);
        }
    }

    if (tid == 0) {
        o_sb[row] = speech_budget;
        o_pb[row] = pause_budget;
        o_cf[row] = conf;
    }
}

extern "C" void kernel_launch(void* const* d_in, const int* in_sizes, int n_in,
                              void* d_out, int out_size, void* d_ws, size_t ws_size,
                              hipStream_t stream) {
    const float* dur   = (const float*)d_in[0];
    const float* stats = (const float*)d_in[1];
    const float* trace = (const float*)d_in[2];
    const float* mask  = (const float*)d_in[3];
    const float* cue   = (const float*)d_in[4];
    float* out = (float*)d_out;

    teacher_kernel<<<dim3(BATCH), dim3(NTH), 0, stream>>>(dur, stats, trace, mask, cue, out);
}

// Round 8
// 153.743 us; speedup vs baseline: 1.1591x; 1.1591x over previous
//
#include <hip/hip_runtime.h>

#define T 8192
#define BATCH 512
#define NTH 1024
#define EPT 8
#define NW 16

typedef float nfloat4 __attribute__((ext_vector_type(4)));

template <int N>
__device__ __forceinline__ void block_reduce(float (&v)[N], float* s_red, float* s_bc) {
    int lane = threadIdx.x & 63, wid = threadIdx.x >> 6;
#pragma unroll
    for (int j = 0; j < N; j++) {
        float x = v[j];
#pragma unroll
        for (int off = 32; off; off >>= 1) x += __shfl_xor(x, off);
        if (lane == 0) s_red[wid * N + j] = x;
    }
    __syncthreads();
    if (threadIdx.x < N) {
        float s = 0.f;
#pragma unroll
        for (int w = 0; w < NW; w++) s += s_red[w * N + threadIdx.x];
        s_bc[threadIdx.x] = s;
    }
    __syncthreads();
}

__global__ __launch_bounds__(NTH) void teacher_kernel(
    const float* __restrict__ dur, const float* __restrict__ stats,
    const float* __restrict__ trace, const float* __restrict__ mask,
    const float* __restrict__ cue, float* __restrict__ out)
{
    const int row = blockIdx.x;
    const int tid = threadIdx.x;
    const int lane = tid & 63, wid = tid >> 6;
    const int base = tid * EPT;

    __shared__ unsigned s_hist[2 * NW * 256];   // 32 KB ping-pong
    __shared__ float s_red[NW * 13];
    __shared__ float s_bc[16];
    __shared__ float s_c0[NTH];                 // each thread's cue[base]
    __shared__ float s_vf[NTH];                 // raw score v[0] per thread
    __shared__ float s_vl[NTH];                 // raw score v[7] per thread
    __shared__ float s_ws[NW];
    __shared__ unsigned s_sel[4];
    __shared__ unsigned s_wu[NW];

    const size_t BT = (size_t)BATCH * T;
    const size_t rbase = (size_t)row * T;

    const float4* m4 = (const float4*)(mask + rbase);
    const float4* d4 = (const float4*)(dur + rbase);
    const float4* c4 = (const float4*)(cue + rbase);
    const float4* t4 = (const float4*)(trace + rbase * 4);

    float* o_sb  = out + 2 * BT;
    float* o_pb  = out + 2 * BT + BATCH;
    float* o_cf  = out + 3 * BT + 2 * BATCH;
    nfloat4* spe4 = (nfloat4*)(out + rbase);
    nfloat4* pae4 = (nfloat4*)(out + BT + rbase);
    nfloat4* al4  = (nfloat4*)(out + 2 * BT + 2 * BATCH + rbase);
    nfloat4* tc4  = ((nfloat4*)(out + 3 * BT + 3 * BATCH)) + rbase;
    nfloat4* pc4  = (nfloat4*)(out + 7 * BT + 3 * BATCH + rbase);
    nfloat4* bk4  = (nfloat4*)(out + 8 * BT + 3 * BATCH + rbase);

    float durr[EPT];
    float acc[12];
#pragma unroll
    for (int j = 0; j < 12; j++) acc[j] = 0.f;
    float statmax = (tid < BATCH) ? fminf(fmaxf(stats[tid * 5 + 4], 0.f), 1.f) : 0.f;

    // ---- Phase 1: full input read (named float4s, explicit components), trace_ctx write, sums
#define P1(jj, M_, D_, C_, TR_) {                                              \
        float m_ = (M_), d_ = (D_), c_ = (C_); float4 tr_ = (TR_);             \
        durr[jj] = d_;                                                         \
        nfloat4 tcv = {tr_.x * m_, tr_.y * m_, tr_.z * m_, tr_.w * m_};        \
        __builtin_nontemporal_store(tcv, &tc4[base + (jj)]);                   \
        acc[0] += m_;              acc[1] += d_ * m_;                          \
        acc[2] += tr_.x * m_;      acc[3] += tr_.x * tr_.x * m_;               \
        acc[4] += tr_.y * m_;      acc[5] += tr_.y * tr_.y * m_;               \
        acc[6] += tr_.z * m_;      acc[7] += tr_.z * tr_.z * m_;               \
        acc[8] += tr_.w * m_;      acc[9] += tr_.w * tr_.w * m_;               \
        acc[10] += c_ * m_;        acc[11] += c_ * tr_.z * m_; }
    {
        float4 mm = m4[tid * 2], dd = d4[tid * 2], cc = c4[tid * 2];
        float4 t0 = t4[base + 0], t1 = t4[base + 1], t2 = t4[base + 2], t3 = t4[base + 3];
        s_c0[tid] = cc.x;
        P1(0, mm.x, dd.x, cc.x, t0);
        P1(1, mm.y, dd.y, cc.y, t1);
        P1(2, mm.z, dd.z, cc.z, t2);
        P1(3, mm.w, dd.w, cc.w, t3);
    }
    {
        float4 mm = m4[tid * 2 + 1], dd = d4[tid * 2 + 1], cc = c4[tid * 2 + 1];
        float4 t0 = t4[base + 4], t1 = t4[base + 5], t2 = t4[base + 6], t3 = t4[base + 7];
        P1(4, mm.x, dd.x, cc.x, t0);
        P1(5, mm.y, dd.y, cc.y, t1);
        P1(6, mm.z, dd.z, cc.z, t2);
        P1(7, mm.w, dd.w, cc.w, t3);
    }
#undef P1
    {
#pragma unroll
        for (int j = 0; j < 12; j++) {
            float x = acc[j];
#pragma unroll
            for (int off = 32; off; off >>= 1) x += __shfl_xor(x, off);
            if (lane == 0) s_red[wid * 13 + j] = x;
        }
        float mx = statmax;
#pragma unroll
        for (int off = 32; off; off >>= 1) mx = fmaxf(mx, __shfl_xor(mx, off));
        if (lane == 0) s_red[wid * 13 + 12] = mx;
        __syncthreads();
        if (tid < 13) {
            float s = s_red[tid];
#pragma unroll
            for (int w = 1; w < NW; w++) {
                float x = s_red[w * 13 + tid];
                s = (tid == 12) ? fmaxf(s, x) : (s + x);
            }
            s_bc[tid] = s;
        }
        __syncthreads();
    }
    const float visible = fmaxf(s_bc[0], 1.f);
    const float sum_d = s_bc[1];
    const float inv_vis = 1.f / visible;
    const float mean0 = s_bc[2] * inv_vis, ex20 = s_bc[3] * inv_vis;
    const float mean1 = s_bc[4] * inv_vis, ex21 = s_bc[5] * inv_vis;
    const float Sz    = s_bc[6];
    const float mean2 = Sz * inv_vis,      ex22 = s_bc[7] * inv_vis;
    const float mean3 = s_bc[8] * inv_vis, ex23 = s_bc[9] * inv_vis;
    const float n1    = s_bc[10];
    const float Scz   = s_bc[11];
    const float gmax  = s_bc[12];
    const float meanc = n1 * inv_vis;

    const float var1_raw = ex21 - mean1 * mean1;
    const float var2_raw = ex22 - mean2 * mean2;
    const float istd0 = 1.f / sqrtf(fmaxf(ex20 - mean0 * mean0, 1e-6f));
    const float istd1 = 1.f / sqrtf(fmaxf(var1_raw, 1e-6f));
    const float istd2 = 1.f / sqrtf(fmaxf(var2_raw, 1e-6f));
    const float istd3 = 1.f / sqrtf(fmaxf(ex23 - mean3 * mean3, 1e-6f));
    const float istdc = 1.f / sqrtf(fmaxf(meanc - meanc * meanc, 1e-6f));

    const int L = (int)(visible + 0.5f);

    const float st0 = stats[row * 5 + 0], st1 = stats[row * 5 + 1];
    const float st2 = stats[row * 5 + 2], st4 = stats[row * 5 + 4];

    const float src_total = fmaxf(sum_d, 1.f);
    const float src_mean = src_total * inv_vis;
    const float ref_ms = fmaxf(st2, 1.f);
    const float rate_scale = fminf(fmaxf(ref_ms / fmaxf(src_mean, 1.f), 0.55f), 1.95f);
    const float speech_budget = src_total * rate_scale;
    const float pause_ratio = fminf(fmaxf(st0, 0.f), 0.49f);
    const float boundary_ratio = fminf(fmaxf(st4, 0.f), 1.f);
    const float mean_pause = fmaxf(st1, 0.f);
    const float pfr = speech_budget * pause_ratio / fmaxf(1.f - pause_ratio, 0.2f);
    const float pfe = visible * boundary_ratio * mean_pause;
    float pause_budget = fmaxf(0.35f * pfr + 0.65f * pfe, 0.f);
    pause_budget = fminf(pause_budget, speech_budget * 0.8f);

    float conf = 0.2f + 0.3f * fminf(fmaxf(st0, 0.f), 1.f)
               + 0.25f * fminf(fmaxf(st4, 0.f), 1.f)
               + 0.2f * mean2
               + 0.1f * expf(-fmaxf(var1_raw, 0.f)) + 0.05f;
    conf = fminf(fmaxf(conf, 0.05f), 1.f);

    const float ratio = fminf(fmaxf(fmaxf(0.3f, gmax), 0.f), 1.f);
    int kint = (int)rintf(visible * ratio);
    kint = max(1, min(kint, L));

    // ---- Closed-form cosine gate (cue is 0/1: sp takes two values hi/lo)
    const float hi = fminf(fmaxf((1.f - meanc) * istdc, -1.5f), 1.5f);
    const float lo = fminf(fmaxf((0.f - meanc) * istdc, -1.5f), 1.5f);
    float pcoef;
    {
        float n0 = visible - n1;
        float sum_sp2 = hi * hi * n1 + lo * lo * n0;
        float sum_rb2 = istd2 * istd2 * visible * fmaxf(var2_raw, 0.f);
        float c1 = Scz - mean2 * n1;
        float c0 = (Sz - mean2 * visible) - c1;
        float dotv = istd2 * (hi * c1 + lo * c0);
        float xn = sqrtf(fmaxf(sum_sp2, 1e-6f));
        float yn = sqrtf(fmaxf(sum_rb2, 1e-6f));
        float agree = fminf(fmaxf(dotv / fmaxf(xn * yn, 1e-6f), -1.f), 1.f);
        float gate = 1.f / (1.f + expf(-(agree - 0.15f) * 4.f));
        pcoef = 0.35f * (0.05f + 0.5f * gate);
    }

    // ---- Phase 3: speech + pause scores (trace/cue reload, named float4s)
    float v[EPT], ps[EPT];
    {
        float4 ca = c4[tid * 2], cb = c4[tid * 2 + 1];
        float cnext = (tid == NTH - 1) ? 1.f : s_c0[tid + 1];
#define P3(ii, C_, PF_, TR_) {                                                  \
        float4 tr_ = (TR_); float vv = 0.f, pp = 0.f;                           \
        if (base + (ii) < L) {                                                  \
            float z1 = (tr_.y - mean1) * istd1;                                 \
            float z3 = (tr_.w - mean3) * istd3;                                 \
            vv = expf(log1pf(fmaxf(durr[ii], 0.f)) + 0.45f * z1 + 0.3f * z3     \
                      + 0.2f * (PF_));                                          \
            float z0 = (tr_.x - mean0) * istd0;                                 \
            float rbv = (tr_.z - mean2) * istd2;                                \
            pp = expf(1.1f * z0 + 1.5f * rbv + pcoef * (lo + (C_) * (hi - lo))); } \
        v[ii] = vv; ps[ii] = pp; }
        {
            float4 t0 = t4[base + 0], t1 = t4[base + 1], t2 = t4[base + 2], t3 = t4[base + 3];
            P3(0, ca.x, ca.y, t0);
            P3(1, ca.y, ca.z, t1);
            P3(2, ca.z, ca.w, t2);
            P3(3, ca.w, cb.x, t3);
        }
        {
            float4 t0 = t4[base + 4], t1 = t4[base + 5], t2 = t4[base + 6], t3 = t4[base + 7];
            P3(4, cb.x, cb.y, t0);
            P3(5, cb.y, cb.z, t1);
            P3(6, cb.z, cb.w, t2);
            P3(7, cb.w, cnext, t3);
        }
#undef P3
    }
    s_vf[tid] = v[0];
    s_vl[tid] = v[7];
    // clear radix hist buffer 0 under the same barrier
    for (int j = tid; j < NW * 256; j += NTH) s_hist[j] = 0u;
    __syncthreads();

    // ---- Phase 3b: smooth3 in-register (edges via LDS); sum
    float acc1[1] = {0.f};
    {
        float prev = (tid > 0) ? s_vl[tid - 1] : 0.f;
        float nxt_edge = (tid < NTH - 1) ? s_vf[tid + 1] : 0.f;
#pragma unroll
        for (int i = 0; i < EPT; i++) {
            float cur = v[i];
            float nxt = (i < 7) ? v[i + 1] : nxt_edge;
            float smv = (base + i < L) ? (prev + cur + nxt) * (1.f / 3.f) : 0.f;
            v[i] = smv; acc1[0] += smv; prev = cur;
        }
    }
    block_reduce<1>(acc1, s_red, s_bc);
    const float spe_scale = speech_budget / fmaxf(s_bc[0], 1e-6f);

    // ---- Phase 4: exact radix select, ping-pong histograms (2 barriers/round)
    unsigned pref = 0u, cmaskk = 0u;
    unsigned kk = (unsigned)kint;
    unsigned cnt_eq = 0u;
    int cur = 0;
#pragma unroll 1
    for (int r = 0; r < 4; r++) {
        const int shift = 24 - 8 * r;
#pragma unroll
        for (int i = 0; i < EPT; i++) {
            unsigned b = __float_as_uint(ps[i]);
            if ((b & cmaskk) == pref)
                atomicAdd(&s_hist[cur * (NW * 256) + wid * 256 + ((b >> shift) & 0xFFu)], 1u);
        }
        __syncthreads();
        if (wid == 0) {
            unsigned bb = lane * 4;
            unsigned h0 = 0, h1 = 0, h2 = 0, h3 = 0;
#pragma unroll
            for (int w = 0; w < NW; w++) {
                h0 += s_hist[cur * (NW * 256) + w * 256 + bb + 0];
                h1 += s_hist[cur * (NW * 256) + w * 256 + bb + 1];
                h2 += s_hist[cur * (NW * 256) + w * 256 + bb + 2];
                h3 += s_hist[cur * (NW * 256) + w * 256 + bb + 3];
            }
            unsigned s = h0 + h1 + h2 + h3;
            unsigned vs = s;
#pragma unroll
            for (int off = 1; off < 64; off <<= 1) {
                unsigned u = __shfl_down(vs, off);
                if (lane + off < 64) vs += u;
            }
            unsigned vnext = __shfl_down(vs, 1);
            if (lane == 63) vnext = 0u;
            unsigned higher = vs - s;
            unsigned S3 = higher + h3;
            unsigned S2 = S3 + h2;
            unsigned S1 = S2 + h1;
            unsigned S0 = S1 + h0;
            if (S3 >= kk && vnext < kk)    { s_sel[0] = bb + 3; s_sel[1] = vnext; s_sel[2] = S3; }
            else if (S2 >= kk && S3 < kk)  { s_sel[0] = bb + 2; s_sel[1] = S3;    s_sel[2] = S2; }
            else if (S1 >= kk && S2 < kk)  { s_sel[0] = bb + 1; s_sel[1] = S2;    s_sel[2] = S1; }
            else if (S0 >= kk && S1 < kk)  { s_sel[0] = bb + 0; s_sel[1] = S1;    s_sel[2] = S0; }
        } else if (r < 3) {
            for (int j = tid - 64; j < NW * 256; j += NTH - 64)
                s_hist[(cur ^ 1) * (NW * 256) + j] = 0u;
        }
        __syncthreads();
        pref |= s_sel[0] << shift;
        cmaskk |= 0xFFu << shift;
        kk -= s_sel[1];
        if (r == 3) cnt_eq = s_sel[2] - s_sel[1];
        cur ^= 1;
    }
    const unsigned thr_bits = pref;
    const unsigned keep_eq = kk;

    // ---- Phase 5: keep top-k; stable ascending-index tie-break only if ties span the cut
    float accp[1] = {0.f};
    if (cnt_eq == keep_eq) {
#pragma unroll
        for (int c = 0; c < EPT; c++) {
            unsigned b = __float_as_uint(ps[c]);
            float pv = (b >= thr_bits) ? ps[c] : 0.f;
            ps[c] = pv; accp[0] += pv;
        }
    } else {
        unsigned teq = 0;
#pragma unroll
        for (int i = 0; i < EPT; i++) teq += (__float_as_uint(ps[i]) == thr_bits) ? 1u : 0u;
        unsigned winc = teq;
#pragma unroll
        for (int off = 1; off < 64; off <<= 1) {
            unsigned u = __shfl_up(winc, off);
            if (lane >= off) winc += u;
        }
        if (lane == 63) s_wu[wid] = winc;
        __syncthreads();
        unsigned rank = winc - teq;
#pragma unroll
        for (int w = 0; w < NW; w++) if (w < wid) rank += s_wu[w];
#pragma unroll
        for (int c = 0; c < EPT; c++) {
            unsigned b = __float_as_uint(ps[c]);
            bool eq = (b == thr_bits);
            bool keep = (b > thr_bits) || (eq && rank < keep_eq);
            if (eq) rank++;
            float pv = keep ? ps[c] : 0.f;
            ps[c] = pv; accp[0] += pv;
        }
    }
    block_reduce<1>(accp, s_red, s_bc);
    const float pa_scale = pause_budget / fmaxf(s_bc[0], 1e-6f);

    // ---- Phase 6: packed writes + thread-local prefix + 1-barrier block scan
    const float inv_alloc = 1.f / fmaxf(speech_budget + pause_budget, 1e-6f);
    float spv[EPT], pav[EPT], alv[EPT], scn[EPT];
    float run = 0.f;
#pragma unroll
    for (int i = 0; i < EPT; i++) {
        bool in = base + i < L;
        float spe = v[i] * spe_scale;
        float pae = ps[i] * pa_scale;
        spv[i] = spe; pav[i] = pae;
        alv[i] = (spe + pae) * inv_alloc;
        run += in ? (spe + pae - durr[i]) : 0.f;
        scn[i] = run;
    }
    {
        nfloat4 a = {spv[0], spv[1], spv[2], spv[3]};
        nfloat4 b = {spv[4], spv[5], spv[6], spv[7]};
        __builtin_nontemporal_store(a, &spe4[tid * 2]);
        __builtin_nontemporal_store(b, &spe4[tid * 2 + 1]);
        nfloat4 c = {pav[0], pav[1], pav[2], pav[3]};
        nfloat4 d = {pav[4], pav[5], pav[6], pav[7]};
        __builtin_nontemporal_store(c, &pae4[tid * 2]);
        __builtin_nontemporal_store(d, &pae4[tid * 2 + 1]);
        nfloat4 e = {alv[0], alv[1], alv[2], alv[3]};
        nfloat4 f = {alv[4], alv[5], alv[6], alv[7]};
        __builtin_nontemporal_store(e, &al4[tid * 2]);
        __builtin_nontemporal_store(f, &al4[tid * 2 + 1]);
    }
    {
        float total = run;
        float winc = total;
#pragma unroll
        for (int off = 1; off < 64; off <<= 1) {
            float u = __shfl_up(winc, off);
            if (lane >= off) winc += u;
        }
        if (lane == 63) s_ws[wid] = winc;
        __syncthreads();
        float off0 = winc - total;
#pragma unroll
        for (int w = 0; w < NW; w++) if (w < wid) off0 += s_ws[w];
        float pcv[EPT], bkv[EPT];
#pragma unroll
        for (int i = 0; i < EPT; i++) {
            bool in = base + i < L;
            float incl = off0 + scn[i];
            pcv[i] = in ? incl : 0.f;
            bkv[i] = in ? fmaxf(incl, 0.f) : 0.f;
        }
        nfloat4 a = {pcv[0], pcv[1], pcv[2], pcv[3]};
        nfloat4 b = {pcv[4], pcv[5], pcv[6], pcv[7]};
        __builtin_nontemporal_store(a, &pc4[tid * 2]);
        __builtin_nontemporal_store(b, &pc4[tid * 2 + 1]);
        nfloat4 c = {bkv[0], bkv[1], bkv[2], bkv[3]};
        nfloat4 d = {bkv[4], bkv[5], bkv[6], bkv[7]};
        __builtin_nontemporal_store(c, &bk4[tid * 2]);
        __builtin_nontemporal_store(d, &bk4[tid * 2 + 1]);
    }

    if (tid == 0) {
        o_sb[row] = speech_budget;
        o_pb[row] = pause_budget;
        o_cf[row] = conf;
    }
}

extern "C" void kernel_launch(void* const* d_in, const int* in_sizes, int n_in,
                              void* d_out, int out_size, void* d_ws, size_t ws_size,
                              hipStream_t stream) {
    const float* dur   = (const float*)d_in[0];
    const float* stats = (const float*)d_in[1];
    const float* trace = (const float*)d_in[2];
    const float* mask  = (const float*)d_in[3];
    const float* cue   = (const float*)d_in[4];
    float* out = (float*)d_out;

    teacher_kernel<<<dim3(BATCH), dim3(NTH), 0, stream>>>(dur, stats, trace, mask, cue, out);
}